// Round 6
// baseline (3095.477 us; speedup 1.0000x reference)
//
#include <hip/hip_runtime.h>

// ---------------------------------------------------------------------------
// 2-layer LSTM (B=64, T=256, D=512, H1=H2=1024) + dense head.
// R6: cached A-loads + per-step buffer_inv (L2 does the broadcast).
// R5 post-mortem: sc1 A-loads sent the 64 MB/step activation broadcast to the
// MALL (200x amplification of ~320 KB unique) -> ~6us/step. Fix: A-loads are
// plain cached loads (manual vmcnt pipeline kept); after observing the epoch
// each block issues `buffer_inv sc1` (agent-acquire invalidate: drops clean
// L1/L2 lines, NO writeback -- unlike R3's threadfence which did wbl2). h
// stores stay sc1 (write-through to MALL, so L2 never holds dirty h and invs
// can't lose data). Fence-free monotone tree barrier unchanged.
// Weights bf16 [col][K] in LDS (loaded once); cell state in registers.
// ---------------------------------------------------------------------------

typedef __bf16 bf16x8 __attribute__((ext_vector_type(8)));
typedef float f32x4 __attribute__((ext_vector_type(4)));
typedef unsigned int u32x4 __attribute__((ext_vector_type(4)));

#define LDS_Z_OFF     131584   // Wlds: 32*(2048+8)*2 = 131584 B
#define LDS_B_OFF     140032   // Zlds: 64*33*4 = 8448 B
#define LDS_TOTAL     140160

__device__ __forceinline__ unsigned short f2bf(float f) {
  unsigned u = __float_as_uint(f);
  unsigned r = (u + 0x7FFFu + ((u >> 16) & 1u)) >> 16;  // RNE (finite inputs)
  return (unsigned short)r;
}

// in: fp32 [R][C] row-major  ->  out: bf16 [C][R] row-major (i.e. B^T layout)
__global__ __launch_bounds__(256) void transpose_to_bf16(
    const float* __restrict__ in, unsigned short* __restrict__ out, int R, int C) {
  __shared__ float tile[32][33];
  int tx = threadIdx.x & 31, ty = threadIdx.x >> 5;  // 32 x 8
  int c0 = blockIdx.x * 32, r0 = blockIdx.y * 32;
#pragma unroll
  for (int i = 0; i < 4; ++i)
    tile[ty + i * 8][tx] = in[(size_t)(r0 + ty + i * 8) * C + (c0 + tx)];
  __syncthreads();
#pragma unroll
  for (int i = 0; i < 4; ++i)
    out[(size_t)(c0 + ty + i * 8) * R + (r0 + tx)] = f2bf(tile[tx][ty + i * 8]);
}

__global__ __launch_bounds__(256) void convert_to_bf16(
    const float* __restrict__ in, unsigned short* __restrict__ out, int n4) {
  int i = blockIdx.x * 256 + threadIdx.x;
  if (i >= n4) return;
  float4 v = reinterpret_cast<const float4*>(in)[i];
  ushort4 o;
  o.x = f2bf(v.x); o.y = f2bf(v.y); o.z = f2bf(v.z); o.w = f2bf(v.w);
  reinterpret_cast<ushort4*>(out)[i] = o;
}

__global__ void init_bar(unsigned* __restrict__ bar) { bar[threadIdx.x] = 0u; }

// ---- manual-pipelined A-load machinery (cached: L1/L2 serve the broadcast;
//      staleness handled by per-step buffer_inv after the barrier) ----------
template <int I, int NPRE, int N0, int DEPTH>
__device__ __forceinline__ void strip_pre(u32x4 (&abuf)[DEPTH],
    const unsigned short* a0, const unsigned short* a1) {
  if constexpr (I < NPRE) {
    constexpr int OFF = (I < N0) ? I * 64 : (I - N0) * 64;
    if constexpr (I < N0)
      asm volatile("global_load_dwordx4 %0, %1, off offset:%2"
                   : "=v"(abuf[I % DEPTH]) : "v"(a0), "i"(OFF));
    else
      asm volatile("global_load_dwordx4 %0, %1, off offset:%2"
                   : "=v"(abuf[I % DEPTH]) : "v"(a1), "i"(OFF));
    strip_pre<I + 1, NPRE, N0, DEPTH>(abuf, a0, a1);
  }
}

template <int KS, int N0, int NTOT, int DEPTH>
__device__ __forceinline__ void strip_iter(u32x4 (&abuf)[DEPTH],
    const unsigned short* a0, const unsigned short* a1,
    const unsigned short* Bp0, const unsigned short* Bp1,
    f32x4& acc0, f32x4& acc1) {
  if constexpr (KS < NTOT) {
    // loads issued so far: min(KS + DEPTH, NTOT); need load KS complete
    constexpr int ISSUED = (KS + DEPTH < NTOT) ? (KS + DEPTH) : NTOT;
    constexpr int WAIT = ISSUED - KS - 1;   // DEPTH-1 steady, tapering tail
    asm volatile("s_waitcnt vmcnt(%1)"
                 : "+v"(abuf[KS % DEPTH]) : "i"(WAIT));
    bf16x8 a = __builtin_bit_cast(bf16x8, abuf[KS % DEPTH]);
    constexpr int KN = KS + DEPTH;          // refill freed slot
    if constexpr (KN < NTOT) {
      constexpr int OFF = (KN < N0) ? KN * 64 : (KN - N0) * 64;
      if constexpr (KN < N0)
        asm volatile("global_load_dwordx4 %0, %1, off offset:%2"
                     : "=v"(abuf[KN % DEPTH]) : "v"(a0), "i"(OFF));
      else
        asm volatile("global_load_dwordx4 %0, %1, off offset:%2"
                     : "=v"(abuf[KN % DEPTH]) : "v"(a1), "i"(OFF));
    }
    bf16x8 w0 = *(const bf16x8*)(Bp0 + KS * 32);
    bf16x8 w1 = *(const bf16x8*)(Bp1 + KS * 32);
    acc0 = __builtin_amdgcn_mfma_f32_16x16x32_bf16(a, w0, acc0, 0, 0, 0);
    acc1 = __builtin_amdgcn_mfma_f32_16x16x32_bf16(a, w1, acc1, 0, 0, 0);
    strip_iter<KS + 1, N0, NTOT, DEPTH>(abuf, a0, a1, Bp0, Bp1, acc0, acc1);
  }
}

template <int N0, int NTOT>
__device__ __forceinline__ void gemm_strip(
    const unsigned short* a0, const unsigned short* a1,
    const unsigned short* Bp0, const unsigned short* Bp1,
    f32x4& acc0, f32x4& acc1) {
  constexpr int DEPTH = 16;
  u32x4 abuf[DEPTH];
  strip_pre<0, (NTOT < DEPTH ? NTOT : DEPTH), N0, DEPTH>(abuf, a0, a1);
  strip_iter<0, N0, NTOT, DEPTH>(abuf, a0, a1, Bp0, Bp1, acc0, acc1);
}

__device__ __forceinline__ void store_h_sc1(unsigned short* p, unsigned v) {
  asm volatile("global_store_short %0, %1, off sc1" :: "v"(p), "v"(v) : "memory");
}

// Fence-free tree barrier + acquire-invalidate.
// bar lines (128B apart): [0]=root, [32*(1+g)]=group ctr, [32*(9+g)]=epoch.
// Monotone counters, no resets. Callers' h stores are sc1 and drained here;
// after the epoch is observed we drop clean L1/L2 lines so the cached A-loads
// of the next step can't see stale h (produced cross-XCD, sc1 = MALL only).
__device__ __forceinline__ void grid_barrier(unsigned* __restrict__ bar,
                                             int g, unsigned want) {
  asm volatile("s_waitcnt vmcnt(0)" ::: "memory");  // h stores acked at MALL
  __syncthreads();
  if (threadIdx.x == 0) {
    unsigned old = __hip_atomic_fetch_add(bar + 32 * (1 + g), 1u,
                                          __ATOMIC_RELAXED, __HIP_MEMORY_SCOPE_AGENT);
    if (old == 32u * want - 1u) {               // last of group
      unsigned r = __hip_atomic_fetch_add(bar, 1u, __ATOMIC_RELAXED,
                                          __HIP_MEMORY_SCOPE_AGENT);
      if (r == 8u * want - 1u) {                // last group -> publish epoch
#pragma unroll
        for (int i = 0; i < 8; ++i)
          __hip_atomic_store(bar + 32 * (9 + i), want, __ATOMIC_RELAXED,
                             __HIP_MEMORY_SCOPE_AGENT);
      }
    }
    while (__hip_atomic_load(bar + 32 * (9 + g), __ATOMIC_RELAXED,
                             __HIP_MEMORY_SCOPE_AGENT) < want)
      __builtin_amdgcn_s_sleep(1);
    // agent-acquire: invalidate clean L1+L2 (no writeback; h is never dirty
    // in L2 because stores are sc1). One per block; L1 is per-CU, L2 per-XCD.
    asm volatile("buffer_inv sc1" ::: "memory");
  }
  __syncthreads();
}

__global__ __launch_bounds__(256, 1) void lstm_persistent(
    const unsigned short* __restrict__ xbf,   // [64][256][512] bf16
    const unsigned short* __restrict__ W1t,   // [4096][512]
    const unsigned short* __restrict__ U1t,   // [4096][1024]
    const float* __restrict__ b1,
    const unsigned short* __restrict__ W2t,   // [4096][1024]
    const unsigned short* __restrict__ U2t,   // [4096][1024]
    const float* __restrict__ b2,
    unsigned short* __restrict__ h1r,         // [2][64][1024] bf16
    unsigned short* __restrict__ h2r,         // [2][64][1024] bf16
    unsigned* __restrict__ bar)
{
  extern __shared__ __align__(16) char smem[];
  const int blk = blockIdx.x;
  const bool is2 = blk >= 128;
  const int lb  = is2 ? blk - 128 : blk;
  const int u0  = lb * 8;                 // first owned unit
  const int K   = is2 ? 2048 : 1536;
  const int pitch = K + 8;
  unsigned short* Wlds = (unsigned short*)smem;          // [32][pitch]
  float* Zlds = (float*)(smem + LDS_Z_OFF);              // [64][33]
  float* Blds = (float*)(smem + LDS_B_OFF);              // [32] bias
  const int g = blk & 7;                  // probable XCD (round-robin); any
                                          // mapping is correct, this is locality
  const int tid = threadIdx.x;

  // ---- one-time: weight slice -> LDS (row r: gate r>>3, unit u0+(r&7)) ----
  {
    const int r = tid >> 3, sub = tid & 7;               // 32 rows x 8 threads
    const int c = (r >> 3) * 1024 + u0 + (r & 7);        // global gate-col
    const unsigned short* wsrc;
    const unsigned short* usrc;
    int wk;
    if (is2) { wsrc = W2t + (size_t)c * 1024; usrc = U2t + (size_t)c * 1024; wk = 1024; }
    else     { wsrc = W1t + (size_t)c * 512;  usrc = U1t + (size_t)c * 1024; wk = 512;  }
    unsigned short* dst = Wlds + r * pitch;
    for (int k = sub * 8; k < wk; k += 64)
      *(uint4*)(dst + k) = *(const uint4*)(wsrc + k);
    for (int k = sub * 8; k < 1024; k += 64)
      *(uint4*)(dst + wk + k) = *(const uint4*)(usrc + k);
    if (tid < 32) {
      const float* bias = is2 ? b2 : b1;
      Blds[tid] = bias[(tid >> 3) * 1024 + u0 + (tid & 7)];
    }
  }
  __syncthreads();

  const int wave = tid >> 6, lane = tid & 63;
  const int quad = lane >> 4, l16 = lane & 15;
  const int m = wave * 16 + l16;                         // batch row (A)
  const unsigned short* Bp0 = Wlds + l16 * pitch + quad * 8;
  const unsigned short* Bp1 = Wlds + (16 + l16) * pitch + quad * 8;

  const int eb = tid >> 3, eu = tid & 7;
  float cLo = 0.f, cHi = 0.f;
  const float bz0 = Blds[eu], bz1 = Blds[8 + eu], bz2 = Blds[16 + eu],
              bz3 = Blds[24 + eu];

  for (int s = 0; s <= 256; ++s) {
    const int t = is2 ? (s - 1) : s;
    if (t >= 0 && t < 256) {
      f32x4 acc0 = {0.f, 0.f, 0.f, 0.f}, acc1 = {0.f, 0.f, 0.f, 0.f};
      if (!is2) {
        const unsigned short* ax =
            xbf + ((size_t)m * 256 + t) * 512 + quad * 8;
        const unsigned short* ah =
            h1r + (size_t)((t - 1) & 1) * 65536 + (size_t)m * 1024 + quad * 8;
        if (t > 0) gemm_strip<16, 48>(ax, ah, Bp0, Bp1, acc0, acc1);
        else       gemm_strip<16, 16>(ax, ax, Bp0, Bp1, acc0, acc1);
      } else {
        const unsigned short* ah1 =
            h1r + (size_t)(t & 1) * 65536 + (size_t)m * 1024 + quad * 8;
        const unsigned short* ah2 =
            h2r + (size_t)((t - 1) & 1) * 65536 + (size_t)m * 1024 + quad * 8;
        if (t > 0) gemm_strip<32, 64>(ah1, ah2, Bp0, Bp1, acc0, acc1);
        else       gemm_strip<32, 32>(ah1, ah1, Bp0, Bp1, acc0, acc1);
      }

      // exchange z across waves: C/D layout col=lane&15, row=quad*4+i
#pragma unroll
      for (int i = 0; i < 4; ++i) {
        Zlds[(wave * 16 + quad * 4 + i) * 33 + l16]      = acc0[i];
        Zlds[(wave * 16 + quad * 4 + i) * 33 + 16 + l16] = acc1[i];
      }
      __syncthreads();

      unsigned short* hring = is2 ? h2r : h1r;
      unsigned short* hp = hring + (size_t)(t & 1) * 65536 + u0 + eu;
      {
        float zi = Zlds[eb * 33 + eu]      + bz0;
        float zf = Zlds[eb * 33 + 8 + eu]  + bz1;
        float zg = Zlds[eb * 33 + 16 + eu] + bz2;
        float zo = Zlds[eb * 33 + 24 + eu] + bz3;
        float ig = 1.f / (1.f + __expf(-zi));
        float fg = 1.f / (1.f + __expf(-zf));
        float gg = 1.f - 2.f / (1.f + __expf(2.f * zg));
        float og = 1.f / (1.f + __expf(-zo));
        cLo = fg * cLo + ig * gg;
        float h = og * (1.f - 2.f / (1.f + __expf(2.f * cLo)));
        store_h_sc1(hp + (size_t)eb * 1024, (unsigned)f2bf(h));
      }
      {
        int br = eb + 32;
        float zi = Zlds[br * 33 + eu]      + bz0;
        float zf = Zlds[br * 33 + 8 + eu]  + bz1;
        float zg = Zlds[br * 33 + 16 + eu] + bz2;
        float zo = Zlds[br * 33 + 24 + eu] + bz3;
        float ig = 1.f / (1.f + __expf(-zi));
        float fg = 1.f / (1.f + __expf(-zf));
        float gg = 1.f - 2.f / (1.f + __expf(2.f * zg));
        float og = 1.f / (1.f + __expf(-zo));
        cHi = fg * cHi + ig * gg;
        float h = og * (1.f - 2.f / (1.f + __expf(2.f * cHi)));
        store_h_sc1(hp + (size_t)br * 1024, (unsigned)f2bf(h));
      }
    }
    if (s < 256) grid_barrier(bar, g, (unsigned)(s + 1));
  }
}

// out[64][512] = h2_last @ Wd + bd.  One wave per 16x16 tile, K=1024.
// (kernel boundary = implicit device-wide acquire; normal cached loads OK)
__global__ __launch_bounds__(64) void dense_kernel(
    const unsigned short* __restrict__ h2,   // [64][1024] bf16
    const unsigned short* __restrict__ Wdt,  // [512][1024] bf16
    const float* __restrict__ bd,
    float* __restrict__ out) {
  int mt = blockIdx.x >> 5;  // 0..3
  int nt = blockIdx.x & 31;  // 0..31
  int lane = threadIdx.x;
  int quad = lane >> 4, l16 = lane & 15;
  f32x4 acc = {0.f, 0.f, 0.f, 0.f};
  const unsigned short* ap = h2 + (size_t)(mt * 16 + l16) * 1024 + quad * 8;
  const unsigned short* bp = Wdt + (size_t)(nt * 16 + l16) * 1024 + quad * 8;
#pragma unroll
  for (int ks = 0; ks < 32; ++ks) {
    bf16x8 a = *reinterpret_cast<const bf16x8*>(ap + ks * 32);
    bf16x8 b = *reinterpret_cast<const bf16x8*>(bp + ks * 32);
    acc = __builtin_amdgcn_mfma_f32_16x16x32_bf16(a, b, acc, 0, 0, 0);
  }
  int colo = nt * 16 + l16;
  float bias = bd[colo];
#pragma unroll
  for (int i = 0; i < 4; ++i)
    out[(size_t)(mt * 16 + quad * 4 + i) * 512 + colo] = acc[i] + bias;
}

extern "C" void kernel_launch(void* const* d_in, const int* in_sizes, int n_in,
                              void* d_out, int out_size, void* d_ws, size_t ws_size,
                              hipStream_t stream) {
  const float* x  = (const float*)d_in[0];
  const float* W1 = (const float*)d_in[1];
  const float* U1 = (const float*)d_in[2];
  const float* b1 = (const float*)d_in[3];
  const float* W2 = (const float*)d_in[4];
  const float* U2 = (const float*)d_in[5];
  const float* b2 = (const float*)d_in[6];
  const float* Wd = (const float*)d_in[7];
  const float* bd = (const float*)d_in[8];
  float* out = (float*)d_out;

  char* p = (char*)d_ws;
  auto carve = [&](size_t bytes) -> char* {
    char* r = p;
    p += (bytes + 255) & ~(size_t)255;
    return r;
  };
  // ~45.5 MiB total (R2-proven budget; R1's 78 MiB overflowed ws)
  unsigned short* W1t = (unsigned short*)carve((size_t)4096 * 512 * 2);
  unsigned short* U1t = (unsigned short*)carve((size_t)4096 * 1024 * 2);
  unsigned short* W2t = (unsigned short*)carve((size_t)4096 * 1024 * 2);
  unsigned short* U2t = (unsigned short*)carve((size_t)4096 * 1024 * 2);
  unsigned short* Wdt = (unsigned short*)carve((size_t)512 * 1024 * 2);
  unsigned short* xbf = (unsigned short*)carve((size_t)64 * 256 * 512 * 2);
  unsigned short* h1r = (unsigned short*)carve((size_t)2 * 64 * 1024 * 2);
  unsigned short* h2r = (unsigned short*)carve((size_t)2 * 64 * 1024 * 2);
  unsigned* bar = (unsigned*)carve(1024 * 4);
  (void)ws_size; (void)in_sizes; (void)n_in; (void)out_size;

  transpose_to_bf16<<<dim3(128, 16), 256, 0, stream>>>(W1, W1t, 512, 4096);
  transpose_to_bf16<<<dim3(128, 32), 256, 0, stream>>>(U1, U1t, 1024, 4096);
  transpose_to_bf16<<<dim3(128, 32), 256, 0, stream>>>(W2, W2t, 1024, 4096);
  transpose_to_bf16<<<dim3(128, 32), 256, 0, stream>>>(U2, U2t, 1024, 4096);
  transpose_to_bf16<<<dim3(16, 32), 256, 0, stream>>>(Wd, Wdt, 1024, 512);
  convert_to_bf16<<<8192, 256, 0, stream>>>(x, xbf, 64 * 256 * 512 / 4);
  init_bar<<<1, 1024, 0, stream>>>(bar);

  hipFuncSetAttribute(reinterpret_cast<const void*>(lstm_persistent),
                      hipFuncAttributeMaxDynamicSharedMemorySize, LDS_TOTAL);
  lstm_persistent<<<256, 256, LDS_TOTAL, stream>>>(
      xbf, W1t, U1t, b1, W2t, U2t, b2, h1r, h2r, bar);

  dense_kernel<<<128, 64, 0, stream>>>(h2r + 65536, Wdt, bd, out);
}

// Round 7
// 1664.542 us; speedup vs baseline: 1.8597x; 1.8597x over previous
//
#include <hip/hip_runtime.h>

// ---------------------------------------------------------------------------
// 2-layer LSTM (B=64, T=256, D=512, H1=H2=1024) + dense head.
// R7: weights in REGISTERS, A staged once per block through LDS.
// R5 (best, 2674us): sc1 A-loads -> 64 MB/step MALL broadcast = 6.4us of the
// 10.25us step. R6 (buffer_inv+cached, 3095us): L2 recycling per step loses.
// Fix: occupancy is 1 wave/SIMD -> ~450 free VGPRs/thread. Each wave holds
// B-frags for 16 cols x full K in VGPRs (256 VGPRs, layer2); block = 64 cols
// x 32 batches; 64 strips x 2 M-halves x 2 layers = 256 blocks. A (32 x K)
// is staged ONCE per block into LDS (sc1 ring, R5-proven), consumed by all 4
// waves via ds_read. A-traffic 64 -> 28 MB/step (24 MB sc1 + 4 MB cached x).
// Fence-free monotone tree barrier + sc1 h stores unchanged from R5.
// ---------------------------------------------------------------------------

typedef __bf16 bf16x8 __attribute__((ext_vector_type(8)));
typedef float f32x4 __attribute__((ext_vector_type(4)));
typedef unsigned int u32x4 __attribute__((ext_vector_type(4)));
typedef unsigned short u16;

#define LDS_Z_OFF 131584   // Alds worst: 32*(2048+8)*2 = 131584 B
#define LDS_TOTAL 140288   // + Zlds 32*68*4 = 8704 B

__device__ __forceinline__ u16 f2bf(float f) {
  unsigned u = __float_as_uint(f);
  unsigned r = (u + 0x7FFFu + ((u >> 16) & 1u)) >> 16;  // RNE (finite inputs)
  return (u16)r;
}

// in: fp32 [R][C] row-major  ->  out: bf16 [C][R] row-major (i.e. B^T layout)
__global__ __launch_bounds__(256) void transpose_to_bf16(
    const float* __restrict__ in, u16* __restrict__ out, int R, int C) {
  __shared__ float tile[32][33];
  int tx = threadIdx.x & 31, ty = threadIdx.x >> 5;  // 32 x 8
  int c0 = blockIdx.x * 32, r0 = blockIdx.y * 32;
#pragma unroll
  for (int i = 0; i < 4; ++i)
    tile[ty + i * 8][tx] = in[(size_t)(r0 + ty + i * 8) * C + (c0 + tx)];
  __syncthreads();
#pragma unroll
  for (int i = 0; i < 4; ++i)
    out[(size_t)(c0 + ty + i * 8) * R + (r0 + tx)] = f2bf(tile[tx][ty + i * 8]);
}

__global__ __launch_bounds__(256) void convert_to_bf16(
    const float* __restrict__ in, u16* __restrict__ out, int n4) {
  int i = blockIdx.x * 256 + threadIdx.x;
  if (i >= n4) return;
  float4 v = reinterpret_cast<const float4*>(in)[i];
  ushort4 o;
  o.x = f2bf(v.x); o.y = f2bf(v.y); o.z = f2bf(v.z); o.w = f2bf(v.w);
  reinterpret_cast<ushort4*>(out)[i] = o;
}

__global__ void init_bar(unsigned* __restrict__ bar) { bar[threadIdx.x] = 0u; }

__device__ __forceinline__ void store_h_sc1(u16* p, unsigned v) {
  asm volatile("global_store_short %0, %1, off sc1" :: "v"(p), "v"(v) : "memory");
}

// ---- A-staging: sc1/cached loads -> LDS via depth-16 ring, manual vmcnt ---
template <int I, int C0, int DEPTH, bool SC0, bool SC1>
__device__ __forceinline__ void stg_issue(u32x4 (&ring)[DEPTH],
    const u16* b0, const u16* b1) {
  constexpr int OFF = (I < C0 ? I : I - C0) * 128;
  if constexpr (I < C0) {
    if constexpr (SC0)
      asm volatile("global_load_dwordx4 %0, %1, off offset:%2 sc1"
                   : "=v"(ring[I % DEPTH]) : "v"(b0), "i"(OFF));
    else
      asm volatile("global_load_dwordx4 %0, %1, off offset:%2"
                   : "=v"(ring[I % DEPTH]) : "v"(b0), "i"(OFF));
  } else {
    if constexpr (SC1)
      asm volatile("global_load_dwordx4 %0, %1, off offset:%2 sc1"
                   : "=v"(ring[I % DEPTH]) : "v"(b1), "i"(OFF));
    else
      asm volatile("global_load_dwordx4 %0, %1, off offset:%2"
                   : "=v"(ring[I % DEPTH]) : "v"(b1), "i"(OFF));
  }
}

template <int I, int NPRE, int C0, int DEPTH, bool SC0, bool SC1>
__device__ __forceinline__ void stg_pre(u32x4 (&ring)[DEPTH],
    const u16* b0, const u16* b1) {
  if constexpr (I < NPRE) {
    stg_issue<I, C0, DEPTH, SC0, SC1>(ring, b0, b1);
    stg_pre<I + 1, NPRE, C0, DEPTH, SC0, SC1>(ring, b0, b1);
  }
}

template <int I, int NC, int C0, int DEPTH, bool SC0, bool SC1>
__device__ __forceinline__ void stg_main(u32x4 (&ring)[DEPTH],
    const u16* b0, const u16* b1, u16* lrow) {
  if constexpr (I < NC) {
    constexpr int ISSUED = (I + DEPTH < NC) ? I + DEPTH : NC;
    constexpr int WAIT = ISSUED - I - 1;
    asm volatile("s_waitcnt vmcnt(%1)" : "+v"(ring[I % DEPTH]) : "i"(WAIT));
    *(u32x4*)(lrow + I * 64) = ring[I % DEPTH];   // ds_write_b128
    if constexpr (I + DEPTH < NC)
      stg_issue<I + DEPTH, C0, DEPTH, SC0, SC1>(ring, b0, b1);
    stg_main<I + 1, NC, C0, DEPTH, SC0, SC1>(ring, b0, b1, lrow);
  }
}

template <int NC, int C0, bool SC0, bool SC1>
__device__ __forceinline__ void stage(const u16* b0, const u16* b1, u16* lrow) {
  u32x4 ring[16];
  stg_pre<0, (NC < 16 ? NC : 16), C0, 16, SC0, SC1>(ring, b0, b1);
  stg_main<0, NC, C0, 16, SC0, SC1>(ring, b0, b1, lrow);
}

// Fence-free tree barrier (R5-proven). bar lines 128B apart: [0]=root,
// [32*(1+g)]=group ctr, [32*(9+g)]=epoch. Monotone counters, no resets.
__device__ __forceinline__ void grid_barrier(unsigned* __restrict__ bar,
                                             int g, unsigned want) {
  asm volatile("s_waitcnt vmcnt(0)" ::: "memory");  // h stores acked at MALL
  __syncthreads();
  if (threadIdx.x == 0) {
    unsigned old = __hip_atomic_fetch_add(bar + 32 * (1 + g), 1u,
                                          __ATOMIC_RELAXED, __HIP_MEMORY_SCOPE_AGENT);
    if (old == 32u * want - 1u) {
      unsigned r = __hip_atomic_fetch_add(bar, 1u, __ATOMIC_RELAXED,
                                          __HIP_MEMORY_SCOPE_AGENT);
      if (r == 8u * want - 1u) {
#pragma unroll
        for (int i = 0; i < 8; ++i)
          __hip_atomic_store(bar + 32 * (9 + i), want, __ATOMIC_RELAXED,
                             __HIP_MEMORY_SCOPE_AGENT);
      }
    }
    while (__hip_atomic_load(bar + 32 * (9 + g), __ATOMIC_RELAXED,
                             __HIP_MEMORY_SCOPE_AGENT) < want)
      __builtin_amdgcn_s_sleep(1);
  }
  __syncthreads();
}

// One layer's persistent loop. NC = K/64 stage chunks, C0 = K0/64 (seg-0).
// Block: 32 batches (mhalf) x 64 gate-cols (strip); wave w = gate w, holds
// B-frags for its 16 units x full K in VGPRs (breg).
template <int NC, int C0, bool SC0, bool IS2>
__device__ __forceinline__ void run_layer(
    const u16* __restrict__ xbf, const u16* __restrict__ Wt,
    const u16* __restrict__ Ut, const float* __restrict__ bias,
    u16* __restrict__ h1r, u16* __restrict__ h2r, unsigned* __restrict__ bar,
    int strip, int mhalf, char* smem, int g) {
  constexpr int K = NC * 64;
  constexpr int P = K + 8;       // LDS row pitch (elements); +16B: bank stagger
  constexpr int NCH = NC * 2;    // MFMA k-chunks (32 elems each)
  constexpr int WCH = C0 * 2;    // k-chunks in W segment
  u16* Alds = (u16*)smem;                       // [32][P]
  float* Zlds = (float*)(smem + LDS_Z_OFF);     // [32][68]
  const int tid = threadIdx.x;
  const int wave = tid >> 6, lane = tid & 63;
  const int quad = lane >> 4, l16 = lane & 15;

  // ---- weights -> registers (once; cached loads, init-time) ----
  bf16x8 breg[NCH];
  const int col = wave * 1024 + strip * 16 + l16;
#pragma unroll
  for (int ks = 0; ks < WCH; ++ks)
    breg[ks] = *(const bf16x8*)(Wt + (size_t)col * (C0 * 64) + ks * 32 + quad * 8);
#pragma unroll
  for (int ks = WCH; ks < NCH; ++ks)
    breg[ks] = *(const bf16x8*)(Ut + (size_t)col * 1024 + (ks - WCH) * 32 + quad * 8);

  // ---- epilogue coords: this thread owns (em,eu) and (em+16,eu) ----
  const int eu = tid & 15, em = tid >> 4;
  const float bz0 = bias[strip * 16 + eu];
  const float bz1 = bias[1024 + strip * 16 + eu];
  const float bz2 = bias[2048 + strip * 16 + eu];
  const float bz3 = bias[3072 + strip * 16 + eu];
  float cA = 0.f, cB = 0.f;

  // ---- staging coords: thread stages row sr, 16B lane l8 ----
  const int sr = tid >> 3, l8 = tid & 7;
  const int sb = mhalf * 32 + sr;               // global batch row
  u16* lrow = Alds + sr * P + l8 * 8;

  const u16* a0p = Alds + l16 * P + quad * 8;
  const u16* a1p = a0p + 16 * P;

  for (int s = 0; s <= 256; ++s) {
    const int t = IS2 ? (s - 1) : s;
    if (t >= 0 && t < 256) {
      const u16 *b0, *b1;
      if constexpr (IS2) {
        b0 = h1r + (size_t)(t & 1) * 65536 + (size_t)sb * 1024 + l8 * 8;
        b1 = h2r + (size_t)((t - 1) & 1) * 65536 + (size_t)sb * 1024 + l8 * 8;
      } else {
        b0 = xbf + ((size_t)sb * 256 + t) * 512 + l8 * 8;
        b1 = h1r + (size_t)((t - 1) & 1) * 65536 + (size_t)sb * 1024 + l8 * 8;
      }
      if (t > 0) {
        stage<NC, C0, SC0, true>(b0, b1, lrow);
      } else {                       // first step: recurrent state is zero
        stage<C0, C0, SC0, true>(b0, b0, lrow);
#pragma unroll
        for (int i = C0; i < NC; ++i)
          *(u32x4*)(lrow + i * 64) = (u32x4){0u, 0u, 0u, 0u};
      }
      __syncthreads();

      f32x4 acc0 = {0.f, 0.f, 0.f, 0.f}, acc1 = {0.f, 0.f, 0.f, 0.f};
#pragma unroll
      for (int ks = 0; ks < NCH; ++ks) {
        bf16x8 a0 = *(const bf16x8*)(a0p + ks * 32);
        bf16x8 a1 = *(const bf16x8*)(a1p + ks * 32);
        acc0 = __builtin_amdgcn_mfma_f32_16x16x32_bf16(a0, breg[ks], acc0, 0, 0, 0);
        acc1 = __builtin_amdgcn_mfma_f32_16x16x32_bf16(a1, breg[ks], acc1, 0, 0, 0);
      }

      // z exchange: C/D layout col=lane&15 (unit), row=quad*4+i (batch)
#pragma unroll
      for (int i = 0; i < 4; ++i) {
        Zlds[(quad * 4 + i) * 68 + wave * 16 + l16] = acc0[i];
        Zlds[(16 + quad * 4 + i) * 68 + wave * 16 + l16] = acc1[i];
      }
      __syncthreads();

      u16* hring = IS2 ? h2r : h1r;
      u16* hp = hring + (size_t)(t & 1) * 65536 +
                (size_t)(mhalf * 32) * 1024 + strip * 16 + eu;
      {
        float zi = Zlds[em * 68 + eu] + bz0;
        float zf = Zlds[em * 68 + 16 + eu] + bz1;
        float zg = Zlds[em * 68 + 32 + eu] + bz2;
        float zo = Zlds[em * 68 + 48 + eu] + bz3;
        float ig = 1.f / (1.f + __expf(-zi));
        float fg = 1.f / (1.f + __expf(-zf));
        float gg = 1.f - 2.f / (1.f + __expf(2.f * zg));
        float og = 1.f / (1.f + __expf(-zo));
        cA = fg * cA + ig * gg;
        float h = og * (1.f - 2.f / (1.f + __expf(2.f * cA)));
        store_h_sc1(hp + (size_t)em * 1024, (unsigned)f2bf(h));
      }
      {
        int m2 = em + 16;
        float zi = Zlds[m2 * 68 + eu] + bz0;
        float zf = Zlds[m2 * 68 + 16 + eu] + bz1;
        float zg = Zlds[m2 * 68 + 32 + eu] + bz2;
        float zo = Zlds[m2 * 68 + 48 + eu] + bz3;
        float ig = 1.f / (1.f + __expf(-zi));
        float fg = 1.f / (1.f + __expf(-zf));
        float gg = 1.f - 2.f / (1.f + __expf(2.f * zg));
        float og = 1.f / (1.f + __expf(-zo));
        cB = fg * cB + ig * gg;
        float h = og * (1.f - 2.f / (1.f + __expf(2.f * cB)));
        store_h_sc1(hp + (size_t)m2 * 1024, (unsigned)f2bf(h));
      }
    }
    if (s < 256) grid_barrier(bar, g, (unsigned)(s + 1));
  }
}

__global__ __launch_bounds__(256, 1) void lstm_persistent(
    const u16* __restrict__ xbf,   // [64][256][512] bf16
    const u16* __restrict__ W1t,   // [4096][512]
    const u16* __restrict__ U1t,   // [4096][1024]
    const float* __restrict__ b1,
    const u16* __restrict__ W2t,   // [4096][1024]
    const u16* __restrict__ U2t,   // [4096][1024]
    const float* __restrict__ b2,
    u16* __restrict__ h1r,         // [2][64][1024] bf16
    u16* __restrict__ h2r,         // [2][64][1024] bf16
    unsigned* __restrict__ bar) {
  extern __shared__ __align__(16) char smem[];
  const int blk = blockIdx.x;
  const bool is2 = blk >= 128;
  const int lb = is2 ? blk - 128 : blk;
  const int strip = lb >> 1;       // 64 col-strips of 16 units
  const int mhalf = lb & 1;        // batch half
  const int g = blk & 7;
  if (!is2)
    run_layer<24, 8, false, false>(xbf, W1t, U1t, b1, h1r, h2r, bar,
                                   strip, mhalf, smem, g);
  else
    run_layer<32, 16, true, true>(xbf, W2t, U2t, b2, h1r, h2r, bar,
                                  strip, mhalf, smem, g);
}

// out[64][512] = h2_last @ Wd + bd.  One wave per 16x16 tile, K=1024.
__global__ __launch_bounds__(64) void dense_kernel(
    const u16* __restrict__ h2,    // [64][1024] bf16
    const u16* __restrict__ Wdt,   // [512][1024] bf16
    const float* __restrict__ bd,
    float* __restrict__ out) {
  int mt = blockIdx.x >> 5;  // 0..3
  int nt = blockIdx.x & 31;  // 0..31
  int lane = threadIdx.x;
  int quad = lane >> 4, l16 = lane & 15;
  f32x4 acc = {0.f, 0.f, 0.f, 0.f};
  const u16* ap = h2 + (size_t)(mt * 16 + l16) * 1024 + quad * 8;
  const u16* bp = Wdt + (size_t)(nt * 16 + l16) * 1024 + quad * 8;
#pragma unroll
  for (int ks = 0; ks < 32; ++ks) {
    bf16x8 a = *reinterpret_cast<const bf16x8*>(ap + ks * 32);
    bf16x8 b = *reinterpret_cast<const bf16x8*>(bp + ks * 32);
    acc = __builtin_amdgcn_mfma_f32_16x16x32_bf16(a, b, acc, 0, 0, 0);
  }
  int colo = nt * 16 + l16;
  float bias = bd[colo];
#pragma unroll
  for (int i = 0; i < 4; ++i)
    out[(size_t)(mt * 16 + quad * 4 + i) * 512 + colo] = acc[i] + bias;
}

extern "C" void kernel_launch(void* const* d_in, const int* in_sizes, int n_in,
                              void* d_out, int out_size, void* d_ws, size_t ws_size,
                              hipStream_t stream) {
  const float* x  = (const float*)d_in[0];
  const float* W1 = (const float*)d_in[1];
  const float* U1 = (const float*)d_in[2];
  const float* b1 = (const float*)d_in[3];
  const float* W2 = (const float*)d_in[4];
  const float* U2 = (const float*)d_in[5];
  const float* b2 = (const float*)d_in[6];
  const float* Wd = (const float*)d_in[7];
  const float* bd = (const float*)d_in[8];
  float* out = (float*)d_out;

  char* p = (char*)d_ws;
  auto carve = [&](size_t bytes) -> char* {
    char* r = p;
    p += (bytes + 255) & ~(size_t)255;
    return r;
  };
  // ~45.5 MiB total (R2-proven budget; R1's 78 MiB overflowed ws)
  u16* W1t = (u16*)carve((size_t)4096 * 512 * 2);
  u16* U1t = (u16*)carve((size_t)4096 * 1024 * 2);
  u16* W2t = (u16*)carve((size_t)4096 * 1024 * 2);
  u16* U2t = (u16*)carve((size_t)4096 * 1024 * 2);
  u16* Wdt = (u16*)carve((size_t)512 * 1024 * 2);
  u16* xbf = (u16*)carve((size_t)64 * 256 * 512 * 2);
  u16* h1r = (u16*)carve((size_t)2 * 64 * 1024 * 2);
  u16* h2r = (u16*)carve((size_t)2 * 64 * 1024 * 2);
  unsigned* bar = (unsigned*)carve(1024 * 4);
  (void)ws_size; (void)in_sizes; (void)n_in; (void)out_size;

  transpose_to_bf16<<<dim3(128, 16), 256, 0, stream>>>(W1, W1t, 512, 4096);
  transpose_to_bf16<<<dim3(128, 32), 256, 0, stream>>>(U1, U1t, 1024, 4096);
  transpose_to_bf16<<<dim3(128, 32), 256, 0, stream>>>(W2, W2t, 1024, 4096);
  transpose_to_bf16<<<dim3(128, 32), 256, 0, stream>>>(U2, U2t, 1024, 4096);
  transpose_to_bf16<<<dim3(16, 32), 256, 0, stream>>>(Wd, Wdt, 1024, 512);
  convert_to_bf16<<<8192, 256, 0, stream>>>(x, xbf, 64 * 256 * 512 / 4);
  init_bar<<<1, 1024, 0, stream>>>(bar);

  hipFuncSetAttribute(reinterpret_cast<const void*>(lstm_persistent),
                      hipFuncAttributeMaxDynamicSharedMemorySize, LDS_TOTAL);
  lstm_persistent<<<256, 256, LDS_TOTAL, stream>>>(
      xbf, W1t, U1t, b1, W2t, U2t, b2, h1r, h2r, bar);

  dense_kernel<<<128, 64, 0, stream>>>(h2r + 65536, Wdt, bd, out);
}